// Round 14
// baseline (847.022 us; speedup 1.0000x reference)
//
#include <hip/hip_runtime.h>

constexpr int H = 1024, W = 1024, FID = 100, NF = 8;
constexpr int NPTS = 1 << 20, KSTEPS = 20;
constexpr int HW = H * W;

constexpr int NTX = 16, NTY = 32, NTILES = NTX * NTY;       // 512 tiles (64x32 px)
constexpr int TPIX = 64 * 32;                               // 2048 px/tile
constexpr int BPT  = 16;                                    // buckets per tile (4-bit)
constexpr int NBINS = NTILES * BPT;                         // 8192 sort bins
constexpr int NBLK = 1024;                                  // phase blocks
constexpr int PPB = NPTS / NBLK;                            // 1024 points/block
constexpr int PPT = PPB / 256;                              // 4 points/thread
constexpr int CHUNK = 32768;                                // records per accum WG
constexpr int TH    = 4096;                                 // dense-tile threshold
constexpr int MAXREC = NPTS * KSTEPS;                       // 20,971,520
constexpr int K4_GRID = MAXREC / CHUNK;                     // 640
constexpr int K4_BS  = 512;                                 // accum block size
constexpr int MAXVIS = K4_GRID + NTILES;                    // 1152 slot cap
constexpr unsigned INV = 0xFFFFFFFFu;
constexpr float QSCALE = 16384.0f;                          // _c fixed-point scale
constexpr float QINV   = 1.0f / 16384.0f;

// decode packed record -> 4 channel values + local pixel
__device__ __forceinline__ void decode_rec(unsigned r, const float4* sPal,
                                           int& pix, float& v0, float& v1,
                                           float& v2, float& v3) {
    pix = (int)(r & 2047u);
    const float _c = (float)(r >> 11) * QINV;       // = c * 100, quantized
    const float cf = floorf(_c);
    const float tt = _c - cf;
    const int cfi = (int)fminf(fmaxf(cf, 0.f), (float)FID);
    const int cci = (int)fminf(fmaxf(ceilf(_c), 0.f), (float)FID);
    const float4 pc = sPal[cci];
    const float4 pf = sPal[cfi];
    const float omt = 1.f - tt;
    v0 = tt * pc.x + omt * pf.x;
    v1 = tt * pc.y + omt * pf.y;
    v2 = tt * pc.z + omt * pf.z;
    v3 = tt * pc.w + omt * pf.w;
}

// ---------- K1: count hits per (bin, block), block-major out; run cache ----------
__global__ __launch_bounds__(256)
void count_kernel(const float* __restrict__ points,
                  const int* __restrict__ choices,
                  const float* __restrict__ A,
                  const float* __restrict__ b,
                  const float* __restrict__ minv,
                  const float* __restrict__ rangev,
                  const int* __restrict__ skipp,
                  unsigned* __restrict__ hist_bm)   // [NBLK][NBINS]
{
    __shared__ float sA[NF * 4], sB[NF * 2];
    __shared__ unsigned shist[NBINS];               // 32 KB
    const int t = threadIdx.x;
    if (t < NF * 4) sA[t] = A[t];
    if (t < NF * 2) sB[t] = b[t];
    for (int i = t; i < NBINS; i += 256) shist[i] = 0u;
    __syncthreads();

    const int blk = blockIdx.x;
    const int base = blk * PPB;
    const float mx = minv[0], my = minv[1], rx = rangev[0], ry = rangev[1];
    const int skip = skipp[0];

    for (int p = 0; p < PPT; ++p) {
        const int n = base + p * 256 + t;
        float x = points[3 * n], y = points[3 * n + 1];
        unsigned cbin = INV, ccnt = 0;
        for (int k = 0; k < KSTEPS; ++k) {
            const int idx = choices[k * NPTS + n];
            const float nx = sA[idx*4+0]*x + sA[idx*4+1]*y + sB[idx*2+0];
            const float ny = sA[idx*4+2]*x + sA[idx*4+3]*y + sB[idx*2+1];
            x = nx; y = ny;
            const int xb = (int)((nx - mx) * rx);
            const int yb = (int)((ny - my) * ry);
            if (k >= skip && (unsigned)xb < (unsigned)W && (unsigned)yb < (unsigned)H) {
                const unsigned tile = (unsigned)(((xb >> 6) << 5) | (yb >> 5));
                const unsigned bin = (tile << 4) | (unsigned)((xb >> 2) & 15);
                if (bin == cbin) { ++ccnt; }
                else {
                    if (cbin != INV) atomicAdd(&shist[cbin], ccnt);
                    cbin = bin; ccnt = 1;
                }
            }
        }
        if (cbin != INV) atomicAdd(&shist[cbin], ccnt);
    }
    __syncthreads();
    unsigned* row = hist_bm + (size_t)blk * NBINS;
    for (int i = t; i < NBINS; i += 256) row[i] = shist[i];   // coalesced
}

// ---------- T: LDS-tiled u32 transpose in[rows][cols] -> out[cols][rows] ----------
__global__ __launch_bounds__(256)
void transpose_kernel(const unsigned* __restrict__ in, unsigned* __restrict__ out,
                      int rows, int cols)
{
    __shared__ unsigned ts[32][33];
    const int tx = threadIdx.x & 31, ty = threadIdx.x >> 5;   // 32x8
    const int c0 = blockIdx.x * 32, r0 = blockIdx.y * 32;
#pragma unroll
    for (int j = 0; j < 32; j += 8)
        ts[ty + j][tx] = in[(size_t)(r0 + ty + j) * cols + c0 + tx];
    __syncthreads();
#pragma unroll
    for (int j = 0; j < 32; j += 8)
        out[(size_t)(c0 + ty + j) * rows + r0 + tx] = ts[tx][ty + j];
}

// ---------- K2a: per-bin (1024-entry) exclusive scan in place; sums[bin] ----------
__global__ __launch_bounds__(1024)
void scan1_kernel(unsigned* __restrict__ hist_binm, unsigned* __restrict__ sums)
{
    __shared__ unsigned buf[2][1024];
    const int t = threadIdx.x;
    const size_t base = (size_t)blockIdx.x * 1024;
    const unsigned v = hist_binm[base + t];
    int src = 0;
    buf[0][t] = v; __syncthreads();
    for (int off = 1; off < 1024; off <<= 1) {
        unsigned val = buf[src][t];
        if (t >= off) val += buf[src][t - off];
        buf[1 - src][t] = val; src ^= 1; __syncthreads();
    }
    const unsigned incl = buf[src][t];
    hist_binm[base + t] = incl - v;
    if (t == 1023) sums[blockIdx.x] = incl;
}

// ---------- K2b: thread t = tile t; scan 16 bin sums each; emit chunkstart/dstart/vstart ----------
__global__ __launch_bounds__(512)
void scan2v_kernel(const unsigned* __restrict__ sums,     // NBINS bin totals
                   unsigned* __restrict__ chunkstart,      // NBINS+1
                   unsigned* __restrict__ dstart,          // NTILES+1
                   unsigned* __restrict__ vstart)          // NTILES+1
{
    __shared__ unsigned buf[2][512];
    const int t = threadIdx.x;
    unsigned s16[BPT];
    unsigned tilelen = 0;
#pragma unroll
    for (int j = 0; j < BPT; ++j) { s16[j] = sums[t * BPT + j]; tilelen += s16[j]; }

    // scan 1: global tile starts
    int src = 0;
    buf[0][t] = tilelen; __syncthreads();
    for (int off = 1; off < 512; off <<= 1) {
        unsigned val = buf[src][t];
        if (t >= off) val += buf[src][t - off];
        buf[1 - src][t] = val; src ^= 1; __syncthreads();
    }
    const unsigned incl = buf[src][t];
    const unsigned excl = incl - tilelen;
    unsigned run = excl;
#pragma unroll
    for (int j = 0; j < BPT; ++j) { chunkstart[t * BPT + j] = run; run += s16[j]; }
    if (t == 511) chunkstart[NBINS] = incl;

    // scan 2: dense-domain starts
    const unsigned dlen = (tilelen >= (unsigned)TH) ? tilelen : 0u;
    __syncthreads();
    buf[0][t] = dlen; src = 0; __syncthreads();
    for (int off = 1; off < 512; off <<= 1) {
        unsigned val = buf[src][t];
        if (t >= off) val += buf[src][t - off];
        buf[1 - src][t] = val; src ^= 1; __syncthreads();
    }
    const unsigned dincl = buf[src][t];
    const unsigned dexcl = dincl - dlen;
    dstart[t] = dexcl;
    if (t == 511) dstart[NTILES] = dincl;

    // scan 3: visit offsets
    unsigned c = 0;
    if (dlen) c = (dexcl + dlen - 1) / CHUNK - dexcl / CHUNK + 1;
    __syncthreads();
    buf[0][t] = c; src = 0; __syncthreads();
    for (int off = 1; off < 512; off <<= 1) {
        unsigned val = buf[src][t];
        if (t >= off) val += buf[src][t - off];
        buf[1 - src][t] = val; src ^= 1; __syncthreads();
    }
    const unsigned vincl = buf[src][t];
    vstart[t] = vincl - c;
    if (t == 511) vstart[NTILES] = vincl;
}

// ---------- K3: scatter packed 4B records into bin-contiguous segments ----------
__global__ __launch_bounds__(256)
void scatter_kernel(const float* __restrict__ points,
                    const int* __restrict__ choices,
                    const float* __restrict__ A,
                    const float* __restrict__ b,
                    const float* __restrict__ fc,
                    const float* __restrict__ minv,
                    const float* __restrict__ rangev,
                    const int* __restrict__ skipp,
                    const unsigned* __restrict__ scanb_bm,  // [NBLK][NBINS] excl within bin
                    const unsigned* __restrict__ chunkstart,
                    unsigned* __restrict__ records)
{
    __shared__ float sA[NF * 4], sB[NF * 2], sFC[NF];
    __shared__ unsigned sCur[NBINS];                // 32 KB
    const int t = threadIdx.x;
    const int blk = blockIdx.x;
    if (t < NF * 4) sA[t] = A[t];
    if (t < NF * 2) sB[t] = b[t];
    if (t < NF)     sFC[t] = fc[t];
    {
        const unsigned* row = scanb_bm + (size_t)blk * NBINS;
        for (int i = t; i < NBINS; i += 256)
            sCur[i] = row[i] + chunkstart[i];       // both coalesced
    }
    __syncthreads();

    const int base = blk * PPB;
    const float mx = minv[0], my = minv[1], rx = rangev[0], ry = rangev[1];
    const int skip = skipp[0];

    for (int p = 0; p < PPT; ++p) {
        const int n = base + p * 256 + t;
        float x = points[3*n], y = points[3*n+1], c = points[3*n+2];
        for (int k = 0; k < KSTEPS; ++k) {
            const int idx = choices[k * NPTS + n];
            const float nx = sA[idx*4+0]*x + sA[idx*4+1]*y + sB[idx*2+0];
            const float ny = sA[idx*4+2]*x + sA[idx*4+3]*y + sB[idx*2+1];
            c = 0.5f * (c + sFC[idx]);
            x = nx; y = ny;
            const int xb = (int)((nx - mx) * rx);
            const int yb = (int)((ny - my) * ry);
            if (k >= skip && (unsigned)xb < (unsigned)W && (unsigned)yb < (unsigned)H) {
                const unsigned tile = (unsigned)(((xb >> 6) << 5) | (yb >> 5));
                const unsigned bin = (tile << 4) | (unsigned)((xb >> 2) & 15);
                const unsigned pos = atomicAdd(&sCur[bin], 1u);
                const unsigned q = (unsigned)__float2int_rn(c * (100.0f * QSCALE));
                records[pos] = (q << 11) | (unsigned)(((xb & 63) << 5) | (yb & 31));
            }
        }
    }
}

// ---------- K4: dense-tile LDS accumulate; bucket-sorted records -> register merge ----------
__global__ __launch_bounds__(K4_BS)
void accum_slot_kernel(const unsigned* __restrict__ records,
                       const unsigned* __restrict__ chunkstart,
                       const unsigned* __restrict__ dstart,
                       const unsigned* __restrict__ vstart,
                       const float* __restrict__ palette,
                       float* __restrict__ slots)
{
    __shared__ float img[4][TPIX];          // 32 KB
    __shared__ float4 sPal[FID + 1];
    __shared__ unsigned tstart[NTILES + 1];
    __shared__ unsigned dst[NTILES + 1];
    __shared__ unsigned vst[NTILES];
    const int t = threadIdx.x;
    for (int i = t; i < NTILES + 1; i += K4_BS) {
        tstart[i] = chunkstart[i * BPT];
        dst[i] = dstart[i];
    }
    for (int i = t; i < NTILES; i += K4_BS) vst[i] = vstart[i];
    for (int i = t; i < (FID + 1) * 4; i += K4_BS) ((float*)sPal)[i] = palette[i];
    __syncthreads();

    const unsigned dtotal = dst[NTILES];
    const unsigned r0 = (unsigned)blockIdx.x * CHUNK;
    if (r0 >= dtotal) return;
    const unsigned r1 = min(r0 + (unsigned)CHUNK, dtotal);

    int lo = 0, hi = NTILES;
    while (lo < hi) {
        const int mid = (lo + hi + 1) >> 1;
        if (dst[mid] <= r0) lo = mid; else hi = mid - 1;
    }

    for (int tile = lo; tile < NTILES && dst[tile] < r1; ++tile) {
        const unsigned sd = max(dst[tile], r0);
        const unsigned ed = min(dst[tile + 1], r1);
        if (sd >= ed) continue;
        const unsigned gs = tstart[tile] + (sd - dst[tile]);
        const unsigned ge = gs + (ed - sd);

        {
            float4* im = (float4*)img;
            const float4 z = {0.f, 0.f, 0.f, 0.f};
            for (int i = t; i < TPIX; i += K4_BS) im[i] = z;
        }
        __syncthreads();

        // register cache: bucket-sorted records make same-pixel runs adjacent
        unsigned cpix = INV;
        float a0 = 0.f, a1 = 0.f, a2 = 0.f, a3 = 0.f;

        for (unsigned i = gs + t; i < ge; i += K4_BS) {
            int pix; float v0, v1, v2, v3;
            decode_rec(records[i], sPal, pix, v0, v1, v2, v3);
            if ((unsigned)pix == cpix) {
                a0 += v0; a1 += v1; a2 += v2; a3 += v3;
            } else {
                if (cpix != INV) {
                    atomicAdd(&img[0][cpix], a0);
                    atomicAdd(&img[1][cpix], a1);
                    atomicAdd(&img[2][cpix], a2);
                    atomicAdd(&img[3][cpix], a3);
                }
                cpix = (unsigned)pix;
                a0 = v0; a1 = v1; a2 = v2; a3 = v3;
            }
        }
        if (cpix != INV) {
            atomicAdd(&img[0][cpix], a0);
            atomicAdd(&img[1][cpix], a1);
            atomicAdd(&img[2][cpix], a2);
            atomicAdd(&img[3][cpix], a3);
        }
        __syncthreads();

        const unsigned slot = vst[tile] + ((unsigned)blockIdx.x - dst[tile] / CHUNK);
        float4* sp = (float4*)(slots + (size_t)slot * (4 * TPIX));
        const float4* im = (const float4*)img;
        for (int i2 = t; i2 < TPIX; i2 += K4_BS)
            sp[i2] = im[i2];
        __syncthreads();
    }
}

// ---------- K5: per-tile reduce of slots + sparse records (+raw0) -> out ----------
__global__ __launch_bounds__(256)
void reduce_kernel(const float* __restrict__ slots,
                   const unsigned* __restrict__ vstart,
                   const unsigned* __restrict__ chunkstart,
                   const unsigned* __restrict__ records,
                   const float* __restrict__ palette,
                   const float* __restrict__ raw0,
                   float* __restrict__ out)
{
    __shared__ float lds[4][256];           // 4 KB sparse accumulator
    __shared__ float4 sPal[FID + 1];
    const int T = blockIdx.x >> 3;          // tile
    const int g = blockIdx.x & 7;           // 256-px group
    const int t = threadIdx.x;
    for (int i = t; i < (FID + 1) * 4; i += 256) ((float*)sPal)[i] = palette[i];
    ((float*)lds)[t] = 0.f; ((float*)lds)[t + 256] = 0.f;
    ((float*)lds)[t + 512] = 0.f; ((float*)lds)[t + 768] = 0.f;
    __syncthreads();

    const unsigned v0 = vstart[T], v1 = vstart[T + 1];
    const unsigned s = chunkstart[T * BPT], e = chunkstart[(T + 1) * BPT];
    const int ch = t >> 6;
    const int f4 = ch * (TPIX / 4) + (g * 256 >> 2) + (t & 63);

    float4 acc = {0.f, 0.f, 0.f, 0.f};
    for (unsigned v = v0; v < v1; ++v) {
        const float4 sv = ((const float4*)(slots + (size_t)v * (4 * TPIX)))[f4];
        acc.x += sv.x; acc.y += sv.y; acc.z += sv.z; acc.w += sv.w;
    }

    if (v0 == v1 && e > s) {
        for (unsigned i = s + t; i < e; i += 256) {
            const unsigned r = records[i];
            const int pix = (int)(r & 2047u);
            if ((pix >> 8) == g) {
                int dummy; float w0, w1, w2, w3;
                decode_rec(r, sPal, dummy, w0, w1, w2, w3);
                const int lp = pix & 255;
                atomicAdd(&lds[0][lp], w0);
                atomicAdd(&lds[1][lp], w1);
                atomicAdd(&lds[2][lp], w2);
                atomicAdd(&lds[3][lp], w3);
            }
        }
    }
    __syncthreads();

    const int lbase = (t & 63) * 4;
    acc.x += lds[ch][lbase + 0];
    acc.y += lds[ch][lbase + 1];
    acc.z += lds[ch][lbase + 2];
    acc.w += lds[ch][lbase + 3];

    const int lpix = g * 256 + lbase;
    const int px = lpix >> 5, py = lpix & 31;
    const int tx = T >> 5, ty = T & 31;
    const size_t o = (size_t)ch * HW + (size_t)(tx * 64 + px) * W + (ty * 32 + py);
    const float4 r = *(const float4*)(raw0 + o);
    acc.x += r.x; acc.y += r.y; acc.z += r.z; acc.w += r.w;
    *(float4*)(out + o) = acc;
}

// ---------- Fallback: direct planar atomics ----------
__global__ __launch_bounds__(256)
void flame_kernel_planar(const float* __restrict__ points,
                         const int* __restrict__ choices,
                         const float* __restrict__ A,
                         const float* __restrict__ b,
                         const float* __restrict__ fc,
                         const float* __restrict__ palette,
                         const float* __restrict__ min_vec,
                         const float* __restrict__ range_vec,
                         const int* __restrict__ skipp,
                         float* __restrict__ out)
{
    __shared__ float sA[NF * 4];
    __shared__ float sB[NF * 2];
    __shared__ float sFC[NF];
    __shared__ float4 sPal[FID + 1];
    const int t = threadIdx.x;
    if (t < NF * 4) sA[t] = A[t];
    if (t < NF * 2) sB[t] = b[t];
    if (t < NF)     sFC[t] = fc[t];
    for (int i = t; i < (FID + 1) * 4; i += 256) ((float*)sPal)[i] = palette[i];
    __syncthreads();

    const int n = blockIdx.x * 256 + t;
    float x = points[3 * n], y = points[3 * n + 1], c = points[3 * n + 2];
    const float mx = min_vec[0], my = min_vec[1];
    const float rx = range_vec[0], ry = range_vec[1];
    const int skip = skipp[0];

    for (int k = 0; k < KSTEPS; ++k) {
        const int idx = choices[k * NPTS + n];
        const float nx = sA[idx*4+0]*x + sA[idx*4+1]*y + sB[idx*2+0];
        const float ny = sA[idx*4+2]*x + sA[idx*4+3]*y + sB[idx*2+1];
        c = 0.5f * (c + sFC[idx]);
        x = nx; y = ny;
        const float _c = c * (float)FID;
        const float cf = floorf(_c);
        const float tt = _c - cf;
        const int cfi = (int)fminf(fmaxf(cf, 0.f), (float)FID);
        const int cci = (int)fminf(fmaxf(ceilf(_c), 0.f), (float)FID);
        const float4 pc = sPal[cci];
        const float4 pf = sPal[cfi];
        const int xb = (int)((nx - mx) * rx);
        const int yb = (int)((ny - my) * ry);
        if (k >= skip && (unsigned)xb < (unsigned)W && (unsigned)yb < (unsigned)H) {
            const int p = xb * W + yb;
            const float omt = 1.f - tt;
            atomicAdd(out + p + 0 * HW, tt * pc.x + omt * pf.x);
            atomicAdd(out + p + 1 * HW, tt * pc.y + omt * pf.y);
            atomicAdd(out + p + 2 * HW, tt * pc.z + omt * pf.z);
            atomicAdd(out + p + 3 * HW, tt * pc.w + omt * pf.w);
        }
    }
}

extern "C" void kernel_launch(void* const* d_in, const int* in_sizes, int n_in,
                              void* d_out, int out_size, void* d_ws, size_t ws_size,
                              hipStream_t stream) {
    const float* points    = (const float*)d_in[0];
    const int*   choices   = (const int*)d_in[1];
    const float* A         = (const float*)d_in[2];
    const float* b         = (const float*)d_in[3];
    const float* fc        = (const float*)d_in[4];
    const float* palette   = (const float*)d_in[5];
    const float* min_vec   = (const float*)d_in[6];
    const float* range_vec = (const float*)d_in[7];
    const float* raw0      = (const float*)d_in[8];
    const int*   skipp     = (const int*)d_in[9];
    float* out = (float*)d_out;
    const size_t img_bytes = (size_t)4 * HW * sizeof(float);   // 16 MB

    // ws layout (tier1): records | hist_bm | hist_binm | small arrays | slots
    const size_t rec_off  = 0;
    const size_t rec_cap  = (size_t)MAXREC * 4;                 // 84 MB
    const size_t hbm_off  = rec_off + rec_cap;
    const size_t hist_sz  = (size_t)NBLK * NBINS * 4;           // 33.6 MB
    const size_t hbin_off = hbm_off + hist_sz;
    const size_t sums_off = hbin_off + hist_sz;                 // NBINS u32
    const size_t cs_off   = sums_off + (size_t)(NBINS + 16) * 4;
    const size_t dst_off  = cs_off + (size_t)(NBINS + 16) * 4;
    const size_t vst_off  = dst_off + 4096;
    const size_t slot_off = vst_off + 4096;
    const size_t slot_cap = (size_t)MAXVIS * (4 * TPIX) * sizeof(float);  // 37 MB
    const size_t need1    = slot_off + slot_cap;                // ~189 MB

    if (ws_size >= need1) {
        unsigned* recs      = (unsigned*)((char*)d_ws + rec_off);
        unsigned* hist_bm   = (unsigned*)((char*)d_ws + hbm_off);
        unsigned* hist_binm = (unsigned*)((char*)d_ws + hbin_off);
        unsigned* sums      = (unsigned*)((char*)d_ws + sums_off);
        unsigned* cstart    = (unsigned*)((char*)d_ws + cs_off);
        unsigned* dstart    = (unsigned*)((char*)d_ws + dst_off);
        unsigned* vstart    = (unsigned*)((char*)d_ws + vst_off);
        float*    slots     = (float*)((char*)d_ws + slot_off);

        count_kernel<<<NBLK, 256, 0, stream>>>(
            points, choices, A, b, min_vec, range_vec, skipp, hist_bm);
        // hist_bm [NBLK][NBINS] -> hist_binm [NBINS][NBLK]
        transpose_kernel<<<dim3(NBINS / 32, NBLK / 32), 256, 0, stream>>>(
            hist_bm, hist_binm, NBLK, NBINS);
        scan1_kernel<<<NBINS, 1024, 0, stream>>>(hist_binm, sums);
        scan2v_kernel<<<1, 512, 0, stream>>>(sums, cstart, dstart, vstart);
        // scanned hist_binm [NBINS][NBLK] -> hist_bm [NBLK][NBINS] (reuse buffer)
        transpose_kernel<<<dim3(NBLK / 32, NBINS / 32), 256, 0, stream>>>(
            hist_binm, hist_bm, NBINS, NBLK);
        scatter_kernel<<<NBLK, 256, 0, stream>>>(
            points, choices, A, b, fc, min_vec, range_vec, skipp,
            hist_bm, cstart, recs);
        accum_slot_kernel<<<K4_GRID, K4_BS, 0, stream>>>(
            recs, cstart, dstart, vstart, palette, slots);
        reduce_kernel<<<NTILES * 8, 256, 0, stream>>>(
            slots, vstart, cstart, recs, palette, raw0, out);
    } else {
        hipMemcpyAsync(out, raw0, img_bytes, hipMemcpyDeviceToDevice, stream);
        flame_kernel_planar<<<NPTS / 256, 256, 0, stream>>>(
            points, choices, A, b, fc, palette, min_vec, range_vec, skipp, out);
    }
}

// Round 15
// 722.151 us; speedup vs baseline: 1.1729x; 1.1729x over previous
//
#include <hip/hip_runtime.h>

constexpr int H = 1024, W = 1024, FID = 100, NF = 8;
constexpr int NPTS = 1 << 20, KSTEPS = 20;
constexpr int HW = H * W;

constexpr int NTX = 16, NTY = 32, NTILES = NTX * NTY;       // 512 tiles (64x32 px)
constexpr int TPIX = 64 * 32;                               // 2048 px/tile
constexpr int NBLK = 1024;                                  // phase blocks
constexpr int PPB = NPTS / NBLK;                            // 1024 points/block
constexpr int PPT = PPB / 256;                              // 4 points/thread
constexpr int SEG_N = NTILES * NBLK;                        // 524,288 segments
constexpr int CHUNK = 8192;                                 // records per accum WG
constexpr int TH    = 4096;                                 // dense-tile threshold
constexpr int MAXREC = NPTS * KSTEPS;                       // 20,971,520
constexpr int K4_GRID = MAXREC / CHUNK;                     // 2560
constexpr int K4_BS  = 512;                                 // accum block size
constexpr int MAXVIS = K4_GRID + NTILES;                    // 3072 slot cap
constexpr unsigned INV = 0xFFFFFFFFu;
constexpr float QSCALE = 16384.0f;                          // _c fixed-point scale
constexpr float QINV   = 1.0f / 16384.0f;

// decode packed record -> 4 channel values + local pixel
__device__ __forceinline__ void decode_rec(unsigned r, const float4* sPal,
                                           int& pix, float& v0, float& v1,
                                           float& v2, float& v3) {
    pix = (int)(r & 2047u);
    const float _c = (float)(r >> 11) * QINV;       // = c * 100, quantized
    const float cf = floorf(_c);
    const float tt = _c - cf;
    const int cfi = (int)fminf(fmaxf(cf, 0.f), (float)FID);
    const int cci = (int)fminf(fmaxf(ceilf(_c), 0.f), (float)FID);
    const float4 pc = sPal[cci];
    const float4 pf = sPal[cfi];
    const float omt = 1.f - tt;
    v0 = tt * pc.x + omt * pf.x;
    v1 = tt * pc.y + omt * pf.y;
    v2 = tt * pc.z + omt * pf.z;
    v3 = tt * pc.w + omt * pf.w;
}

// ---------- K1: count hits per (tile, block); per-thread run cache ----------
__global__ __launch_bounds__(256)
void count_kernel(const float* __restrict__ points,
                  const int* __restrict__ choices,
                  const float* __restrict__ A,
                  const float* __restrict__ b,
                  const float* __restrict__ minv,
                  const float* __restrict__ rangev,
                  const int* __restrict__ skipp,
                  unsigned* __restrict__ hist)
{
    __shared__ float sA[NF * 4], sB[NF * 2];
    __shared__ unsigned shist[4][NTILES];
    const int t = threadIdx.x;
    if (t < NF * 4) sA[t] = A[t];
    if (t < NF * 2) sB[t] = b[t];
    for (int i = t; i < 4 * NTILES; i += 256) ((unsigned*)shist)[i] = 0u;
    __syncthreads();

    const int blk = blockIdx.x;
    const int base = blk * PPB;
    const float mx = minv[0], my = minv[1], rx = rangev[0], ry = rangev[1];
    const int skip = skipp[0];
    const int wv = t >> 6;

    for (int p = 0; p < PPT; ++p) {
        const int n = base + p * 256 + t;
        float x = points[3 * n], y = points[3 * n + 1];
        unsigned ctile = INV, ccnt = 0;
        for (int k = 0; k < KSTEPS; ++k) {
            const int idx = choices[k * NPTS + n];
            const float nx = sA[idx*4+0]*x + sA[idx*4+1]*y + sB[idx*2+0];
            const float ny = sA[idx*4+2]*x + sA[idx*4+3]*y + sB[idx*2+1];
            x = nx; y = ny;
            const int xb = (int)((nx - mx) * rx);
            const int yb = (int)((ny - my) * ry);
            if (k >= skip && (unsigned)xb < (unsigned)W && (unsigned)yb < (unsigned)H) {
                const unsigned tile = (unsigned)(((xb >> 6) << 5) | (yb >> 5));
                if (tile == ctile) { ++ccnt; }
                else {
                    if (ctile != INV) atomicAdd(&shist[wv][ctile], ccnt);
                    ctile = tile; ccnt = 1;
                }
            }
        }
        if (ctile != INV) atomicAdd(&shist[wv][ctile], ccnt);
    }
    __syncthreads();
    for (int tt = t; tt < NTILES; tt += 256)
        hist[tt * NBLK + blk] =
            shist[0][tt] + shist[1][tt] + shist[2][tt] + shist[3][tt];
}

// ---------- K2a: per-1024-chunk exclusive scan (in place); 1 chunk == 1 tile ----------
__global__ __launch_bounds__(1024)
void scan1_kernel(unsigned* __restrict__ hist, unsigned* __restrict__ sums)
{
    __shared__ unsigned buf[2][1024];
    const int t = threadIdx.x;
    const int base = blockIdx.x * 1024;
    const unsigned v = hist[base + t];
    int src = 0;
    buf[0][t] = v; __syncthreads();
    for (int off = 1; off < 1024; off <<= 1) {
        unsigned val = buf[src][t];
        if (t >= off) val += buf[src][t - off];
        buf[1 - src][t] = val; src ^= 1; __syncthreads();
    }
    const unsigned incl = buf[src][t];
    hist[base + t] = incl - v;
    if (t == 1023) sums[blockIdx.x] = incl;
}

// ---------- K2b: 3 scans — global starts, dense starts, visit offsets ----------
__global__ __launch_bounds__(512)
void scan2v_kernel(unsigned* __restrict__ sums,
                   unsigned* __restrict__ dstart,
                   unsigned* __restrict__ vstart)
{
    __shared__ unsigned buf[2][512];
    const int t = threadIdx.x;
    const unsigned len = sums[t];

    int src = 0;
    buf[0][t] = len; __syncthreads();
    for (int off = 1; off < 512; off <<= 1) {
        unsigned val = buf[src][t];
        if (t >= off) val += buf[src][t - off];
        buf[1 - src][t] = val; src ^= 1; __syncthreads();
    }
    unsigned incl = buf[src][t];
    sums[t] = incl - len;
    if (t == 511) sums[512] = incl;

    const unsigned dlen = (len >= (unsigned)TH) ? len : 0u;
    __syncthreads();
    buf[0][t] = dlen; src = 0; __syncthreads();
    for (int off = 1; off < 512; off <<= 1) {
        unsigned val = buf[src][t];
        if (t >= off) val += buf[src][t - off];
        buf[1 - src][t] = val; src ^= 1; __syncthreads();
    }
    unsigned dincl = buf[src][t];
    const unsigned dexcl = dincl - dlen;
    dstart[t] = dexcl;
    if (t == 511) dstart[512] = dincl;

    unsigned c = 0;
    if (dlen) c = (dexcl + dlen - 1) / CHUNK - dexcl / CHUNK + 1;
    __syncthreads();
    buf[0][t] = c; src = 0; __syncthreads();
    for (int off = 1; off < 512; off <<= 1) {
        unsigned val = buf[src][t];
        if (t >= off) val += buf[src][t - off];
        buf[1 - src][t] = val; src ^= 1; __syncthreads();
    }
    unsigned vincl = buf[src][t];
    vstart[t] = vincl - c;
    if (t == 511) vstart[512] = vincl;
}

// ---------- K3: scatter packed 4B records into tile-contiguous segments ----------
__global__ __launch_bounds__(256)
void scatter_kernel(const float* __restrict__ points,
                    const int* __restrict__ choices,
                    const float* __restrict__ A,
                    const float* __restrict__ b,
                    const float* __restrict__ fc,
                    const float* __restrict__ minv,
                    const float* __restrict__ rangev,
                    const int* __restrict__ skipp,
                    const unsigned* __restrict__ scanb,   // = hist after scan
                    const unsigned* __restrict__ sums,
                    unsigned* __restrict__ records)
{
    __shared__ float sA[NF * 4], sB[NF * 2], sFC[NF];
    __shared__ unsigned sCur[NTILES];
    const int t = threadIdx.x;
    const int blk = blockIdx.x;
    if (t < NF * 4) sA[t] = A[t];
    if (t < NF * 2) sB[t] = b[t];
    if (t < NF)     sFC[t] = fc[t];
    for (int tt = t; tt < NTILES; tt += 256)
        sCur[tt] = scanb[tt * NBLK + blk] + sums[tt];
    __syncthreads();

    const int base = blk * PPB;
    const float mx = minv[0], my = minv[1], rx = rangev[0], ry = rangev[1];
    const int skip = skipp[0];

    for (int p = 0; p < PPT; ++p) {
        const int n = base + p * 256 + t;
        float x = points[3*n], y = points[3*n+1], c = points[3*n+2];
        for (int k = 0; k < KSTEPS; ++k) {
            const int idx = choices[k * NPTS + n];
            const float nx = sA[idx*4+0]*x + sA[idx*4+1]*y + sB[idx*2+0];
            const float ny = sA[idx*4+2]*x + sA[idx*4+3]*y + sB[idx*2+1];
            c = 0.5f * (c + sFC[idx]);
            x = nx; y = ny;
            const int xb = (int)((nx - mx) * rx);
            const int yb = (int)((ny - my) * ry);
            if (k >= skip && (unsigned)xb < (unsigned)W && (unsigned)yb < (unsigned)H) {
                const int tile = ((xb >> 6) << 5) | (yb >> 5);
                const unsigned pos = atomicAdd(&sCur[tile], 1u);
                const unsigned q = (unsigned)__float2int_rn(c * (100.0f * QSCALE));
                records[pos] = (q << 11) | (unsigned)(((xb & 63) << 5) | (yb & 31));
            }
        }
    }
}

// ---------- K4: dense-tile LDS accumulate, small chunks, plain atomics ----------
__global__ __launch_bounds__(K4_BS)
void accum_slot_kernel(const unsigned* __restrict__ records,
                       const unsigned* __restrict__ sums,
                       const unsigned* __restrict__ dstart,
                       const unsigned* __restrict__ vstart,
                       const float* __restrict__ palette,
                       float* __restrict__ slots)
{
    __shared__ float img[4][TPIX];          // 32 KB
    __shared__ float4 sPal[FID + 1];
    __shared__ unsigned tstart[NTILES + 1];
    __shared__ unsigned dst[NTILES + 1];
    __shared__ unsigned vst[NTILES];
    const int t = threadIdx.x;
    for (int i = t; i < NTILES + 1; i += K4_BS) { tstart[i] = sums[i]; dst[i] = dstart[i]; }
    for (int i = t; i < NTILES; i += K4_BS) vst[i] = vstart[i];
    for (int i = t; i < (FID + 1) * 4; i += K4_BS) ((float*)sPal)[i] = palette[i];
    __syncthreads();

    const unsigned dtotal = dst[NTILES];
    const unsigned r0 = (unsigned)blockIdx.x * CHUNK;
    if (r0 >= dtotal) return;
    const unsigned r1 = min(r0 + (unsigned)CHUNK, dtotal);

    int lo = 0, hi = NTILES;
    while (lo < hi) {
        const int mid = (lo + hi + 1) >> 1;
        if (dst[mid] <= r0) lo = mid; else hi = mid - 1;
    }

    for (int tile = lo; tile < NTILES && dst[tile] < r1; ++tile) {
        const unsigned sd = max(dst[tile], r0);
        const unsigned ed = min(dst[tile + 1], r1);
        if (sd >= ed) continue;
        const unsigned gs = tstart[tile] + (sd - dst[tile]);
        const unsigned ge = gs + (ed - sd);

        {
            float4* im = (float4*)img;
            const float4 z = {0.f, 0.f, 0.f, 0.f};
            for (int i = t; i < TPIX; i += K4_BS) im[i] = z;
        }
        __syncthreads();

        // plain loop: no loop-carried state -> compiler can pipeline loads
        for (unsigned i = gs + t; i < ge; i += K4_BS) {
            int pix; float v0, v1, v2, v3;
            decode_rec(records[i], sPal, pix, v0, v1, v2, v3);
            atomicAdd(&img[0][pix], v0);
            atomicAdd(&img[1][pix], v1);
            atomicAdd(&img[2][pix], v2);
            atomicAdd(&img[3][pix], v3);
        }
        __syncthreads();

        const unsigned slot = vst[tile] + ((unsigned)blockIdx.x - dst[tile] / CHUNK);
        float4* sp = (float4*)(slots + (size_t)slot * (4 * TPIX));
        const float4* im = (const float4*)img;
        for (int i2 = t; i2 < TPIX; i2 += K4_BS)
            sp[i2] = im[i2];
        __syncthreads();
    }
}

// ---------- K5: per-tile reduce of slots + sparse records (+raw0) -> out ----------
__global__ __launch_bounds__(256)
void reduce_kernel(const float* __restrict__ slots,
                   const unsigned* __restrict__ vstart,
                   const unsigned* __restrict__ sums,
                   const unsigned* __restrict__ records,
                   const float* __restrict__ palette,
                   const float* __restrict__ raw0,
                   float* __restrict__ out)
{
    __shared__ float lds[4][256];           // 4 KB sparse accumulator
    __shared__ float4 sPal[FID + 1];
    const int T = blockIdx.x >> 3;          // tile
    const int g = blockIdx.x & 7;           // 256-px group
    const int t = threadIdx.x;
    for (int i = t; i < (FID + 1) * 4; i += 256) ((float*)sPal)[i] = palette[i];
    ((float*)lds)[t] = 0.f; ((float*)lds)[t + 256] = 0.f;
    ((float*)lds)[t + 512] = 0.f; ((float*)lds)[t + 768] = 0.f;
    __syncthreads();

    const unsigned v0 = vstart[T], v1 = vstart[T + 1];
    const unsigned s = sums[T], e = sums[T + 1];
    const int ch = t >> 6;
    const int f4 = ch * (TPIX / 4) + (g * 256 >> 2) + (t & 63);

    float4 acc = {0.f, 0.f, 0.f, 0.f};
    for (unsigned v = v0; v < v1; ++v) {
        const float4 sv = ((const float4*)(slots + (size_t)v * (4 * TPIX)))[f4];
        acc.x += sv.x; acc.y += sv.y; acc.z += sv.z; acc.w += sv.w;
    }

    if (v0 == v1 && e > s) {
        for (unsigned i = s + t; i < e; i += 256) {
            const unsigned r = records[i];
            const int pix = (int)(r & 2047u);
            if ((pix >> 8) == g) {
                int dummy; float w0, w1, w2, w3;
                decode_rec(r, sPal, dummy, w0, w1, w2, w3);
                const int lp = pix & 255;
                atomicAdd(&lds[0][lp], w0);
                atomicAdd(&lds[1][lp], w1);
                atomicAdd(&lds[2][lp], w2);
                atomicAdd(&lds[3][lp], w3);
            }
        }
    }
    __syncthreads();

    const int lbase = (t & 63) * 4;
    acc.x += lds[ch][lbase + 0];
    acc.y += lds[ch][lbase + 1];
    acc.z += lds[ch][lbase + 2];
    acc.w += lds[ch][lbase + 3];

    const int lpix = g * 256 + lbase;
    const int px = lpix >> 5, py = lpix & 31;
    const int tx = T >> 5, ty = T & 31;
    const size_t o = (size_t)ch * HW + (size_t)(tx * 64 + px) * W + (ty * 32 + py);
    const float4 r = *(const float4*)(raw0 + o);
    acc.x += r.x; acc.y += r.y; acc.z += r.z; acc.w += r.w;
    *(float4*)(out + o) = acc;
}

// ---------- Fallback: direct planar atomics ----------
__global__ __launch_bounds__(256)
void flame_kernel_planar(const float* __restrict__ points,
                         const int* __restrict__ choices,
                         const float* __restrict__ A,
                         const float* __restrict__ b,
                         const float* __restrict__ fc,
                         const float* __restrict__ palette,
                         const float* __restrict__ min_vec,
                         const float* __restrict__ range_vec,
                         const int* __restrict__ skipp,
                         float* __restrict__ out)
{
    __shared__ float sA[NF * 4];
    __shared__ float sB[NF * 2];
    __shared__ float sFC[NF];
    __shared__ float4 sPal[FID + 1];
    const int t = threadIdx.x;
    if (t < NF * 4) sA[t] = A[t];
    if (t < NF * 2) sB[t] = b[t];
    if (t < NF)     sFC[t] = fc[t];
    for (int i = t; i < (FID + 1) * 4; i += 256) ((float*)sPal)[i] = palette[i];
    __syncthreads();

    const int n = blockIdx.x * 256 + t;
    float x = points[3 * n], y = points[3 * n + 1], c = points[3 * n + 2];
    const float mx = min_vec[0], my = min_vec[1];
    const float rx = range_vec[0], ry = range_vec[1];
    const int skip = skipp[0];

    for (int k = 0; k < KSTEPS; ++k) {
        const int idx = choices[k * NPTS + n];
        const float nx = sA[idx*4+0]*x + sA[idx*4+1]*y + sB[idx*2+0];
        const float ny = sA[idx*4+2]*x + sA[idx*4+3]*y + sB[idx*2+1];
        c = 0.5f * (c + sFC[idx]);
        x = nx; y = ny;
        const float _c = c * (float)FID;
        const float cf = floorf(_c);
        const float tt = _c - cf;
        const int cfi = (int)fminf(fmaxf(cf, 0.f), (float)FID);
        const int cci = (int)fminf(fmaxf(ceilf(_c), 0.f), (float)FID);
        const float4 pc = sPal[cci];
        const float4 pf = sPal[cfi];
        const int xb = (int)((nx - mx) * rx);
        const int yb = (int)((ny - my) * ry);
        if (k >= skip && (unsigned)xb < (unsigned)W && (unsigned)yb < (unsigned)H) {
            const int p = xb * W + yb;
            const float omt = 1.f - tt;
            atomicAdd(out + p + 0 * HW, tt * pc.x + omt * pf.x);
            atomicAdd(out + p + 1 * HW, tt * pc.y + omt * pf.y);
            atomicAdd(out + p + 2 * HW, tt * pc.z + omt * pf.z);
            atomicAdd(out + p + 3 * HW, tt * pc.w + omt * pf.w);
        }
    }
}

extern "C" void kernel_launch(void* const* d_in, const int* in_sizes, int n_in,
                              void* d_out, int out_size, void* d_ws, size_t ws_size,
                              hipStream_t stream) {
    const float* points    = (const float*)d_in[0];
    const int*   choices   = (const int*)d_in[1];
    const float* A         = (const float*)d_in[2];
    const float* b         = (const float*)d_in[3];
    const float* fc        = (const float*)d_in[4];
    const float* palette   = (const float*)d_in[5];
    const float* min_vec   = (const float*)d_in[6];
    const float* range_vec = (const float*)d_in[7];
    const float* raw0      = (const float*)d_in[8];
    const int*   skipp     = (const int*)d_in[9];
    float* out = (float*)d_out;
    const size_t img_bytes = (size_t)4 * HW * sizeof(float);   // 16 MB

    const size_t hist_off = 0;                                  // 2 MiB
    const size_t rec_off  = (size_t)SEG_N * 4;
    const size_t rec_cap  = (size_t)MAXREC * 4;                 // 84 MB (u32 records)
    const size_t sums_off = rec_off + rec_cap;
    const size_t dst_off  = sums_off + 4096;
    const size_t vst_off  = dst_off + 4096;
    const size_t slot_off = vst_off + 4096;
    const size_t slot_cap = (size_t)MAXVIS * (4 * TPIX) * sizeof(float);  // 100.7 MB
    const size_t need1    = slot_off + slot_cap;               // ~187 MB

    unsigned* hist = (unsigned*)((char*)d_ws + hist_off);
    unsigned* sums = (unsigned*)((char*)d_ws + sums_off);
    unsigned* recs = (unsigned*)((char*)d_ws + rec_off);

    if (ws_size >= need1) {
        unsigned* dstart = (unsigned*)((char*)d_ws + dst_off);
        unsigned* vstart = (unsigned*)((char*)d_ws + vst_off);
        float*    slots  = (float*)((char*)d_ws + slot_off);

        count_kernel<<<NBLK, 256, 0, stream>>>(
            points, choices, A, b, min_vec, range_vec, skipp, hist);
        scan1_kernel<<<SEG_N / 1024, 1024, 0, stream>>>(hist, sums);
        scan2v_kernel<<<1, 512, 0, stream>>>(sums, dstart, vstart);
        scatter_kernel<<<NBLK, 256, 0, stream>>>(
            points, choices, A, b, fc, min_vec, range_vec, skipp, hist, sums, recs);
        accum_slot_kernel<<<K4_GRID, K4_BS, 0, stream>>>(
            recs, sums, dstart, vstart, palette, slots);
        reduce_kernel<<<NTILES * 8, 256, 0, stream>>>(
            slots, vstart, sums, recs, palette, raw0, out);
    } else {
        hipMemcpyAsync(out, raw0, img_bytes, hipMemcpyDeviceToDevice, stream);
        flame_kernel_planar<<<NPTS / 256, 256, 0, stream>>>(
            points, choices, A, b, fc, palette, min_vec, range_vec, skipp, out);
    }
}

// Round 16
// 412.638 us; speedup vs baseline: 2.0527x; 1.7501x over previous
//
#include <hip/hip_runtime.h>

constexpr int H = 1024, W = 1024, FID = 100, NF = 8;
constexpr int NPTS = 1 << 20, KSTEPS = 20;
constexpr int HW = H * W;

constexpr int NTX = 16, NTY = 32, NTILES = NTX * NTY;       // 512 tiles (64x32 px)
constexpr int TPIX = 64 * 32;                               // 2048 px/tile
constexpr int NBLK = 1024;                                  // phase blocks
constexpr int PPB = NPTS / NBLK;                            // 1024 points/block
constexpr int PPT = PPB / 256;                              // 4 points/thread
constexpr int SEG_N = NTILES * NBLK;                        // 524,288 segments
constexpr int CHUNK = 8192;                                 // records per accum WG
constexpr int TH    = 4096;                                 // dense-tile threshold
constexpr int MAXREC = NPTS * KSTEPS;                       // 20,971,520
constexpr int K4_GRID = MAXREC / CHUNK;                     // 2560
constexpr int K4_BS  = 512;                                 // accum block size
constexpr int MAXVIS = K4_GRID + NTILES;                    // 3072 slot cap
constexpr unsigned INV = 0xFFFFFFFFu;
constexpr float QSCALE = 16384.0f;                          // _c fixed-point scale
constexpr float QINV   = 1.0f / 16384.0f;
constexpr float FXS  = 131072.0f;                           // 2^17 channel fixed-point
constexpr float FXSI = 1.0f / 131072.0f;

// decode packed record -> 4 channel values + local pixel
__device__ __forceinline__ void decode_rec(unsigned r, const float4* sPal,
                                           int& pix, float& v0, float& v1,
                                           float& v2, float& v3) {
    pix = (int)(r & 2047u);
    const float _c = (float)(r >> 11) * QINV;       // = c * 100, quantized
    const float cf = floorf(_c);
    const float tt = _c - cf;
    const int cfi = (int)fminf(fmaxf(cf, 0.f), (float)FID);
    const int cci = (int)fminf(fmaxf(ceilf(_c), 0.f), (float)FID);
    const float4 pc = sPal[cci];
    const float4 pf = sPal[cfi];
    const float omt = 1.f - tt;
    v0 = tt * pc.x + omt * pf.x;
    v1 = tt * pc.y + omt * pf.y;
    v2 = tt * pc.z + omt * pf.z;
    v3 = tt * pc.w + omt * pf.w;
}

__device__ __forceinline__ unsigned long long pack2(float a, float b) {
    const unsigned ua = __float2uint_rn(a * FXS);
    const unsigned ub = __float2uint_rn(b * FXS);
    return (unsigned long long)ua | ((unsigned long long)ub << 32);
}

// ---------- K1: count hits per (tile, block); per-thread run cache ----------
__global__ __launch_bounds__(256)
void count_kernel(const float* __restrict__ points,
                  const int* __restrict__ choices,
                  const float* __restrict__ A,
                  const float* __restrict__ b,
                  const float* __restrict__ minv,
                  const float* __restrict__ rangev,
                  const int* __restrict__ skipp,
                  unsigned* __restrict__ hist)
{
    __shared__ float sA[NF * 4], sB[NF * 2];
    __shared__ unsigned shist[4][NTILES];
    const int t = threadIdx.x;
    if (t < NF * 4) sA[t] = A[t];
    if (t < NF * 2) sB[t] = b[t];
    for (int i = t; i < 4 * NTILES; i += 256) ((unsigned*)shist)[i] = 0u;
    __syncthreads();

    const int blk = blockIdx.x;
    const int base = blk * PPB;
    const float mx = minv[0], my = minv[1], rx = rangev[0], ry = rangev[1];
    const int skip = skipp[0];
    const int wv = t >> 6;

    for (int p = 0; p < PPT; ++p) {
        const int n = base + p * 256 + t;
        float x = points[3 * n], y = points[3 * n + 1];
        unsigned ctile = INV, ccnt = 0;
        for (int k = 0; k < KSTEPS; ++k) {
            const int idx = choices[k * NPTS + n];
            const float nx = sA[idx*4+0]*x + sA[idx*4+1]*y + sB[idx*2+0];
            const float ny = sA[idx*4+2]*x + sA[idx*4+3]*y + sB[idx*2+1];
            x = nx; y = ny;
            const int xb = (int)((nx - mx) * rx);
            const int yb = (int)((ny - my) * ry);
            if (k >= skip && (unsigned)xb < (unsigned)W && (unsigned)yb < (unsigned)H) {
                const unsigned tile = (unsigned)(((xb >> 6) << 5) | (yb >> 5));
                if (tile == ctile) { ++ccnt; }
                else {
                    if (ctile != INV) atomicAdd(&shist[wv][ctile], ccnt);
                    ctile = tile; ccnt = 1;
                }
            }
        }
        if (ctile != INV) atomicAdd(&shist[wv][ctile], ccnt);
    }
    __syncthreads();
    for (int tt = t; tt < NTILES; tt += 256)
        hist[tt * NBLK + blk] =
            shist[0][tt] + shist[1][tt] + shist[2][tt] + shist[3][tt];
}

// ---------- K2a: per-1024-chunk exclusive scan (in place); 1 chunk == 1 tile ----------
__global__ __launch_bounds__(1024)
void scan1_kernel(unsigned* __restrict__ hist, unsigned* __restrict__ sums)
{
    __shared__ unsigned buf[2][1024];
    const int t = threadIdx.x;
    const int base = blockIdx.x * 1024;
    const unsigned v = hist[base + t];
    int src = 0;
    buf[0][t] = v; __syncthreads();
    for (int off = 1; off < 1024; off <<= 1) {
        unsigned val = buf[src][t];
        if (t >= off) val += buf[src][t - off];
        buf[1 - src][t] = val; src ^= 1; __syncthreads();
    }
    const unsigned incl = buf[src][t];
    hist[base + t] = incl - v;
    if (t == 1023) sums[blockIdx.x] = incl;
}

// ---------- K2b: 3 scans — global starts, dense starts, visit offsets ----------
__global__ __launch_bounds__(512)
void scan2v_kernel(unsigned* __restrict__ sums,
                   unsigned* __restrict__ dstart,
                   unsigned* __restrict__ vstart)
{
    __shared__ unsigned buf[2][512];
    const int t = threadIdx.x;
    const unsigned len = sums[t];

    int src = 0;
    buf[0][t] = len; __syncthreads();
    for (int off = 1; off < 512; off <<= 1) {
        unsigned val = buf[src][t];
        if (t >= off) val += buf[src][t - off];
        buf[1 - src][t] = val; src ^= 1; __syncthreads();
    }
    unsigned incl = buf[src][t];
    sums[t] = incl - len;
    if (t == 511) sums[512] = incl;

    const unsigned dlen = (len >= (unsigned)TH) ? len : 0u;
    __syncthreads();
    buf[0][t] = dlen; src = 0; __syncthreads();
    for (int off = 1; off < 512; off <<= 1) {
        unsigned val = buf[src][t];
        if (t >= off) val += buf[src][t - off];
        buf[1 - src][t] = val; src ^= 1; __syncthreads();
    }
    unsigned dincl = buf[src][t];
    const unsigned dexcl = dincl - dlen;
    dstart[t] = dexcl;
    if (t == 511) dstart[512] = dincl;

    unsigned c = 0;
    if (dlen) c = (dexcl + dlen - 1) / CHUNK - dexcl / CHUNK + 1;
    __syncthreads();
    buf[0][t] = c; src = 0; __syncthreads();
    for (int off = 1; off < 512; off <<= 1) {
        unsigned val = buf[src][t];
        if (t >= off) val += buf[src][t - off];
        buf[1 - src][t] = val; src ^= 1; __syncthreads();
    }
    unsigned vincl = buf[src][t];
    vstart[t] = vincl - c;
    if (t == 511) vstart[512] = vincl;
}

// ---------- K3: scatter packed 4B records into tile-contiguous segments ----------
__global__ __launch_bounds__(256)
void scatter_kernel(const float* __restrict__ points,
                    const int* __restrict__ choices,
                    const float* __restrict__ A,
                    const float* __restrict__ b,
                    const float* __restrict__ fc,
                    const float* __restrict__ minv,
                    const float* __restrict__ rangev,
                    const int* __restrict__ skipp,
                    const unsigned* __restrict__ scanb,   // = hist after scan
                    const unsigned* __restrict__ sums,
                    unsigned* __restrict__ records)
{
    __shared__ float sA[NF * 4], sB[NF * 2], sFC[NF];
    __shared__ unsigned sCur[NTILES];
    const int t = threadIdx.x;
    const int blk = blockIdx.x;
    if (t < NF * 4) sA[t] = A[t];
    if (t < NF * 2) sB[t] = b[t];
    if (t < NF)     sFC[t] = fc[t];
    for (int tt = t; tt < NTILES; tt += 256)
        sCur[tt] = scanb[tt * NBLK + blk] + sums[tt];
    __syncthreads();

    const int base = blk * PPB;
    const float mx = minv[0], my = minv[1], rx = rangev[0], ry = rangev[1];
    const int skip = skipp[0];

    for (int p = 0; p < PPT; ++p) {
        const int n = base + p * 256 + t;
        float x = points[3*n], y = points[3*n+1], c = points[3*n+2];
        for (int k = 0; k < KSTEPS; ++k) {
            const int idx = choices[k * NPTS + n];
            const float nx = sA[idx*4+0]*x + sA[idx*4+1]*y + sB[idx*2+0];
            const float ny = sA[idx*4+2]*x + sA[idx*4+3]*y + sB[idx*2+1];
            c = 0.5f * (c + sFC[idx]);
            x = nx; y = ny;
            const int xb = (int)((nx - mx) * rx);
            const int yb = (int)((ny - my) * ry);
            if (k >= skip && (unsigned)xb < (unsigned)W && (unsigned)yb < (unsigned)H) {
                const int tile = ((xb >> 6) << 5) | (yb >> 5);
                const unsigned pos = atomicAdd(&sCur[tile], 1u);
                const unsigned q = (unsigned)__float2int_rn(c * (100.0f * QSCALE));
                records[pos] = (q << 11) | (unsigned)(((xb & 63) << 5) | (yb & 31));
            }
        }
    }
}

// ---------- K4: dense-tile LDS accumulate, u64 packed fixed-point atomics ----------
__global__ __launch_bounds__(K4_BS)
void accum_slot_kernel(const unsigned* __restrict__ records,
                       const unsigned* __restrict__ sums,
                       const unsigned* __restrict__ dstart,
                       const unsigned* __restrict__ vstart,
                       const float* __restrict__ palette,
                       float* __restrict__ slots)
{
    __shared__ unsigned long long img01[TPIX];   // ch0|ch1 packed, 16 KB
    __shared__ unsigned long long img23[TPIX];   // ch2|ch3 packed, 16 KB
    __shared__ float4 sPal[FID + 1];
    __shared__ unsigned tstart[NTILES + 1];
    __shared__ unsigned dst[NTILES + 1];
    __shared__ unsigned vst[NTILES];
    const int t = threadIdx.x;
    for (int i = t; i < NTILES + 1; i += K4_BS) { tstart[i] = sums[i]; dst[i] = dstart[i]; }
    for (int i = t; i < NTILES; i += K4_BS) vst[i] = vstart[i];
    for (int i = t; i < (FID + 1) * 4; i += K4_BS) ((float*)sPal)[i] = palette[i];
    __syncthreads();

    const unsigned dtotal = dst[NTILES];
    const unsigned r0 = (unsigned)blockIdx.x * CHUNK;
    if (r0 >= dtotal) return;
    const unsigned r1 = min(r0 + (unsigned)CHUNK, dtotal);

    int lo = 0, hi = NTILES;
    while (lo < hi) {
        const int mid = (lo + hi + 1) >> 1;
        if (dst[mid] <= r0) lo = mid; else hi = mid - 1;
    }

    for (int tile = lo; tile < NTILES && dst[tile] < r1; ++tile) {
        const unsigned sd = max(dst[tile], r0);
        const unsigned ed = min(dst[tile + 1], r1);
        if (sd >= ed) continue;
        const unsigned gs = tstart[tile] + (sd - dst[tile]);
        const unsigned ge = gs + (ed - sd);

        for (int i = t; i < TPIX; i += K4_BS) { img01[i] = 0ull; img23[i] = 0ull; }
        __syncthreads();

        // 2 u64 atomics per record (was 4 f32) — halves DS-atomic op count.
        // Fixed-point 2^17: 8192 adds x 2^17 = 2^30 < 2^31, fields can't carry.
        for (unsigned i = gs + t; i < ge; i += K4_BS) {
            int pix; float v0, v1, v2, v3;
            decode_rec(records[i], sPal, pix, v0, v1, v2, v3);
            atomicAdd(&img01[pix], pack2(v0, v1));
            atomicAdd(&img23[pix], pack2(v2, v3));
        }
        __syncthreads();

        // flush: unpack to the 4-plane slot layout with coalesced stores
        const unsigned slot = vst[tile] + ((unsigned)blockIdx.x - dst[tile] / CHUNK);
        float* sp = slots + (size_t)slot * (4 * TPIX);
        for (int i2 = t; i2 < TPIX; i2 += K4_BS) {
            const unsigned long long a = img01[i2];
            const unsigned long long bb = img23[i2];
            sp[0 * TPIX + i2] = (float)(unsigned)(a  & 0xFFFFFFFFu) * FXSI;
            sp[1 * TPIX + i2] = (float)(unsigned)(a  >> 32)         * FXSI;
            sp[2 * TPIX + i2] = (float)(unsigned)(bb & 0xFFFFFFFFu) * FXSI;
            sp[3 * TPIX + i2] = (float)(unsigned)(bb >> 32)         * FXSI;
        }
        __syncthreads();
    }
}

// ---------- K5: per-tile reduce of slots + sparse records (+raw0) -> out ----------
__global__ __launch_bounds__(256)
void reduce_kernel(const float* __restrict__ slots,
                   const unsigned* __restrict__ vstart,
                   const unsigned* __restrict__ sums,
                   const unsigned* __restrict__ records,
                   const float* __restrict__ palette,
                   const float* __restrict__ raw0,
                   float* __restrict__ out)
{
    __shared__ unsigned long long l01[256];      // sparse acc, ch0|ch1
    __shared__ unsigned long long l23[256];      // sparse acc, ch2|ch3
    __shared__ float4 sPal[FID + 1];
    const int T = blockIdx.x >> 3;          // tile
    const int g = blockIdx.x & 7;           // 256-px group
    const int t = threadIdx.x;
    for (int i = t; i < (FID + 1) * 4; i += 256) ((float*)sPal)[i] = palette[i];
    l01[t] = 0ull; l23[t] = 0ull;
    __syncthreads();

    const unsigned v0 = vstart[T], v1 = vstart[T + 1];
    const unsigned s = sums[T], e = sums[T + 1];
    const int ch = t >> 6;
    const int f4 = ch * (TPIX / 4) + (g * 256 >> 2) + (t & 63);

    float4 acc = {0.f, 0.f, 0.f, 0.f};
    for (unsigned v = v0; v < v1; ++v) {
        const float4 sv = ((const float4*)(slots + (size_t)v * (4 * TPIX)))[f4];
        acc.x += sv.x; acc.y += sv.y; acc.z += sv.z; acc.w += sv.w;
    }

    if (v0 == v1 && e > s) {
        // sparse tile (≤4096 records): 2^17 fixed-point safe (4096*2^17 = 2^29)
        for (unsigned i = s + t; i < e; i += 256) {
            const unsigned r = records[i];
            const int pix = (int)(r & 2047u);
            if ((pix >> 8) == g) {
                int dummy; float w0, w1, w2, w3;
                decode_rec(r, sPal, dummy, w0, w1, w2, w3);
                const int lp = pix & 255;
                atomicAdd(&l01[lp], pack2(w0, w1));
                atomicAdd(&l23[lp], pack2(w2, w3));
            }
        }
    }
    __syncthreads();

    const int lbase = (t & 63) * 4;
#pragma unroll
    for (int j = 0; j < 4; ++j) {
        const int lp = lbase + j;
        float v;
        if (ch == 0)      v = (float)(unsigned)(l01[lp] & 0xFFFFFFFFu) * FXSI;
        else if (ch == 1) v = (float)(unsigned)(l01[lp] >> 32) * FXSI;
        else if (ch == 2) v = (float)(unsigned)(l23[lp] & 0xFFFFFFFFu) * FXSI;
        else              v = (float)(unsigned)(l23[lp] >> 32) * FXSI;
        if (j == 0) acc.x += v;
        else if (j == 1) acc.y += v;
        else if (j == 2) acc.z += v;
        else acc.w += v;
    }

    const int lpix = g * 256 + lbase;
    const int px = lpix >> 5, py = lpix & 31;
    const int tx = T >> 5, ty = T & 31;
    const size_t o = (size_t)ch * HW + (size_t)(tx * 64 + px) * W + (ty * 32 + py);
    const float4 r = *(const float4*)(raw0 + o);
    acc.x += r.x; acc.y += r.y; acc.z += r.z; acc.w += r.w;
    *(float4*)(out + o) = acc;
}

// ---------- Fallback: direct planar atomics ----------
__global__ __launch_bounds__(256)
void flame_kernel_planar(const float* __restrict__ points,
                         const int* __restrict__ choices,
                         const float* __restrict__ A,
                         const float* __restrict__ b,
                         const float* __restrict__ fc,
                         const float* __restrict__ palette,
                         const float* __restrict__ min_vec,
                         const float* __restrict__ range_vec,
                         const int* __restrict__ skipp,
                         float* __restrict__ out)
{
    __shared__ float sA[NF * 4];
    __shared__ float sB[NF * 2];
    __shared__ float sFC[NF];
    __shared__ float4 sPal[FID + 1];
    const int t = threadIdx.x;
    if (t < NF * 4) sA[t] = A[t];
    if (t < NF * 2) sB[t] = b[t];
    if (t < NF)     sFC[t] = fc[t];
    for (int i = t; i < (FID + 1) * 4; i += 256) ((float*)sPal)[i] = palette[i];
    __syncthreads();

    const int n = blockIdx.x * 256 + t;
    float x = points[3 * n], y = points[3 * n + 1], c = points[3 * n + 2];
    const float mx = min_vec[0], my = min_vec[1];
    const float rx = range_vec[0], ry = range_vec[1];
    const int skip = skipp[0];

    for (int k = 0; k < KSTEPS; ++k) {
        const int idx = choices[k * NPTS + n];
        const float nx = sA[idx*4+0]*x + sA[idx*4+1]*y + sB[idx*2+0];
        const float ny = sA[idx*4+2]*x + sA[idx*4+3]*y + sB[idx*2+1];
        c = 0.5f * (c + sFC[idx]);
        x = nx; y = ny;
        const float _c = c * (float)FID;
        const float cf = floorf(_c);
        const float tt = _c - cf;
        const int cfi = (int)fminf(fmaxf(cf, 0.f), (float)FID);
        const int cci = (int)fminf(fmaxf(ceilf(_c), 0.f), (float)FID);
        const float4 pc = sPal[cci];
        const float4 pf = sPal[cfi];
        const int xb = (int)((nx - mx) * rx);
        const int yb = (int)((ny - my) * ry);
        if (k >= skip && (unsigned)xb < (unsigned)W && (unsigned)yb < (unsigned)H) {
            const int p = xb * W + yb;
            const float omt = 1.f - tt;
            atomicAdd(out + p + 0 * HW, tt * pc.x + omt * pf.x);
            atomicAdd(out + p + 1 * HW, tt * pc.y + omt * pf.y);
            atomicAdd(out + p + 2 * HW, tt * pc.z + omt * pf.z);
            atomicAdd(out + p + 3 * HW, tt * pc.w + omt * pf.w);
        }
    }
}

extern "C" void kernel_launch(void* const* d_in, const int* in_sizes, int n_in,
                              void* d_out, int out_size, void* d_ws, size_t ws_size,
                              hipStream_t stream) {
    const float* points    = (const float*)d_in[0];
    const int*   choices   = (const int*)d_in[1];
    const float* A         = (const float*)d_in[2];
    const float* b         = (const float*)d_in[3];
    const float* fc        = (const float*)d_in[4];
    const float* palette   = (const float*)d_in[5];
    const float* min_vec   = (const float*)d_in[6];
    const float* range_vec = (const float*)d_in[7];
    const float* raw0      = (const float*)d_in[8];
    const int*   skipp     = (const int*)d_in[9];
    float* out = (float*)d_out;
    const size_t img_bytes = (size_t)4 * HW * sizeof(float);   // 16 MB

    const size_t hist_off = 0;                                  // 2 MiB
    const size_t rec_off  = (size_t)SEG_N * 4;
    const size_t rec_cap  = (size_t)MAXREC * 4;                 // 84 MB (u32 records)
    const size_t sums_off = rec_off + rec_cap;
    const size_t dst_off  = sums_off + 4096;
    const size_t vst_off  = dst_off + 4096;
    const size_t slot_off = vst_off + 4096;
    const size_t slot_cap = (size_t)MAXVIS * (4 * TPIX) * sizeof(float);  // 100.7 MB
    const size_t need1    = slot_off + slot_cap;               // ~187 MB

    unsigned* hist = (unsigned*)((char*)d_ws + hist_off);
    unsigned* sums = (unsigned*)((char*)d_ws + sums_off);
    unsigned* recs = (unsigned*)((char*)d_ws + rec_off);

    if (ws_size >= need1) {
        unsigned* dstart = (unsigned*)((char*)d_ws + dst_off);
        unsigned* vstart = (unsigned*)((char*)d_ws + vst_off);
        float*    slots  = (float*)((char*)d_ws + slot_off);

        count_kernel<<<NBLK, 256, 0, stream>>>(
            points, choices, A, b, min_vec, range_vec, skipp, hist);
        scan1_kernel<<<SEG_N / 1024, 1024, 0, stream>>>(hist, sums);
        scan2v_kernel<<<1, 512, 0, stream>>>(sums, dstart, vstart);
        scatter_kernel<<<NBLK, 256, 0, stream>>>(
            points, choices, A, b, fc, min_vec, range_vec, skipp, hist, sums, recs);
        accum_slot_kernel<<<K4_GRID, K4_BS, 0, stream>>>(
            recs, sums, dstart, vstart, palette, slots);
        reduce_kernel<<<NTILES * 8, 256, 0, stream>>>(
            slots, vstart, sums, recs, palette, raw0, out);
    } else {
        hipMemcpyAsync(out, raw0, img_bytes, hipMemcpyDeviceToDevice, stream);
        flame_kernel_planar<<<NPTS / 256, 256, 0, stream>>>(
            points, choices, A, b, fc, palette, min_vec, range_vec, skipp, out);
    }
}

// Round 17
// 410.695 us; speedup vs baseline: 2.0624x; 1.0047x over previous
//
#include <hip/hip_runtime.h>

constexpr int H = 1024, W = 1024, FID = 100, NF = 8;
constexpr int NPTS = 1 << 20, KSTEPS = 20;
constexpr int HW = H * W;

constexpr int NTX = 16, NTY = 32, NTILES = NTX * NTY;       // 512 tiles (64x32 px)
constexpr int TPIX = 64 * 32;                               // 2048 px/tile
constexpr int NBLK = 1024;                                  // phase blocks
constexpr int PPB = NPTS / NBLK;                            // 1024 points/block
constexpr int PPT = PPB / 256;                              // 4 points/thread
constexpr int SEG_N = NTILES * NBLK;                        // 524,288 segments
constexpr int CHUNK = 8192;                                 // records per accum WG
constexpr int TH    = 4096;                                 // dense-tile threshold
constexpr int MAXREC = NPTS * KSTEPS;                       // 20,971,520
constexpr int K4_GRID = MAXREC / CHUNK;                     // 2560
constexpr int K4_BS  = 512;                                 // accum block size
constexpr int MAXVIS = K4_GRID + NTILES;                    // 3072 slot cap
constexpr int RBCAP = KSTEPS;                               // run buffer slots/thread
constexpr unsigned INV = 0xFFFFFFFFu;
constexpr float QSCALE = 16384.0f;                          // _c fixed-point scale
constexpr float QINV   = 1.0f / 16384.0f;
constexpr float FXS  = 131072.0f;                           // 2^17 channel fixed-point
constexpr float FXSI = 1.0f / 131072.0f;

// decode packed record -> 4 channel values + local pixel
__device__ __forceinline__ void decode_rec(unsigned r, const float4* sPal,
                                           int& pix, float& v0, float& v1,
                                           float& v2, float& v3) {
    pix = (int)(r & 2047u);
    const float _c = (float)(r >> 11) * QINV;       // = c * 100, quantized
    const float cf = floorf(_c);
    const float tt = _c - cf;
    const int cfi = (int)fminf(fmaxf(cf, 0.f), (float)FID);
    const int cci = (int)fminf(fmaxf(ceilf(_c), 0.f), (float)FID);
    const float4 pc = sPal[cci];
    const float4 pf = sPal[cfi];
    const float omt = 1.f - tt;
    v0 = tt * pc.x + omt * pf.x;
    v1 = tt * pc.y + omt * pf.y;
    v2 = tt * pc.z + omt * pf.z;
    v3 = tt * pc.w + omt * pf.w;
}

__device__ __forceinline__ unsigned long long pack2(float a, float b) {
    const unsigned ua = __float2uint_rn(a * FXS);
    const unsigned ub = __float2uint_rn(b * FXS);
    return (unsigned long long)ua | ((unsigned long long)ub << 32);
}

// ---------- K1: count hits per (tile, block); per-thread run cache ----------
__global__ __launch_bounds__(256)
void count_kernel(const float* __restrict__ points,
                  const int* __restrict__ choices,
                  const float* __restrict__ A,
                  const float* __restrict__ b,
                  const float* __restrict__ minv,
                  const float* __restrict__ rangev,
                  const int* __restrict__ skipp,
                  unsigned* __restrict__ hist)
{
    __shared__ float sA[NF * 4], sB[NF * 2];
    __shared__ unsigned shist[4][NTILES];
    const int t = threadIdx.x;
    if (t < NF * 4) sA[t] = A[t];
    if (t < NF * 2) sB[t] = b[t];
    for (int i = t; i < 4 * NTILES; i += 256) ((unsigned*)shist)[i] = 0u;
    __syncthreads();

    const int blk = blockIdx.x;
    const int base = blk * PPB;
    const float mx = minv[0], my = minv[1], rx = rangev[0], ry = rangev[1];
    const int skip = skipp[0];
    const int wv = t >> 6;

    for (int p = 0; p < PPT; ++p) {
        const int n = base + p * 256 + t;
        float x = points[3 * n], y = points[3 * n + 1];
        unsigned ctile = INV, ccnt = 0;
        for (int k = 0; k < KSTEPS; ++k) {
            const int idx = choices[k * NPTS + n];
            const float nx = sA[idx*4+0]*x + sA[idx*4+1]*y + sB[idx*2+0];
            const float ny = sA[idx*4+2]*x + sA[idx*4+3]*y + sB[idx*2+1];
            x = nx; y = ny;
            const int xb = (int)((nx - mx) * rx);
            const int yb = (int)((ny - my) * ry);
            if (k >= skip && (unsigned)xb < (unsigned)W && (unsigned)yb < (unsigned)H) {
                const unsigned tile = (unsigned)(((xb >> 6) << 5) | (yb >> 5));
                if (tile == ctile) { ++ccnt; }
                else {
                    if (ctile != INV) atomicAdd(&shist[wv][ctile], ccnt);
                    ctile = tile; ccnt = 1;
                }
            }
        }
        if (ctile != INV) atomicAdd(&shist[wv][ctile], ccnt);
    }
    __syncthreads();
    for (int tt = t; tt < NTILES; tt += 256)
        hist[tt * NBLK + blk] =
            shist[0][tt] + shist[1][tt] + shist[2][tt] + shist[3][tt];
}

// ---------- K2a: per-1024-chunk exclusive scan (in place); 1 chunk == 1 tile ----------
__global__ __launch_bounds__(1024)
void scan1_kernel(unsigned* __restrict__ hist, unsigned* __restrict__ sums)
{
    __shared__ unsigned buf[2][1024];
    const int t = threadIdx.x;
    const int base = blockIdx.x * 1024;
    const unsigned v = hist[base + t];
    int src = 0;
    buf[0][t] = v; __syncthreads();
    for (int off = 1; off < 1024; off <<= 1) {
        unsigned val = buf[src][t];
        if (t >= off) val += buf[src][t - off];
        buf[1 - src][t] = val; src ^= 1; __syncthreads();
    }
    const unsigned incl = buf[src][t];
    hist[base + t] = incl - v;
    if (t == 1023) sums[blockIdx.x] = incl;
}

// ---------- K2b: 3 scans — global starts, dense starts, visit offsets ----------
__global__ __launch_bounds__(512)
void scan2v_kernel(unsigned* __restrict__ sums,
                   unsigned* __restrict__ dstart,
                   unsigned* __restrict__ vstart)
{
    __shared__ unsigned buf[2][512];
    const int t = threadIdx.x;
    const unsigned len = sums[t];

    int src = 0;
    buf[0][t] = len; __syncthreads();
    for (int off = 1; off < 512; off <<= 1) {
        unsigned val = buf[src][t];
        if (t >= off) val += buf[src][t - off];
        buf[1 - src][t] = val; src ^= 1; __syncthreads();
    }
    unsigned incl = buf[src][t];
    sums[t] = incl - len;
    if (t == 511) sums[512] = incl;

    const unsigned dlen = (len >= (unsigned)TH) ? len : 0u;
    __syncthreads();
    buf[0][t] = dlen; src = 0; __syncthreads();
    for (int off = 1; off < 512; off <<= 1) {
        unsigned val = buf[src][t];
        if (t >= off) val += buf[src][t - off];
        buf[1 - src][t] = val; src ^= 1; __syncthreads();
    }
    unsigned dincl = buf[src][t];
    const unsigned dexcl = dincl - dlen;
    dstart[t] = dexcl;
    if (t == 511) dstart[512] = dincl;

    unsigned c = 0;
    if (dlen) c = (dexcl + dlen - 1) / CHUNK - dexcl / CHUNK + 1;
    __syncthreads();
    buf[0][t] = c; src = 0; __syncthreads();
    for (int off = 1; off < 512; off <<= 1) {
        unsigned val = buf[src][t];
        if (t >= off) val += buf[src][t - off];
        buf[1 - src][t] = val; src ^= 1; __syncthreads();
    }
    unsigned vincl = buf[src][t];
    vstart[t] = vincl - c;
    if (t == 511) vstart[512] = vincl;
}

// ---------- K3: scatter w/ per-thread LDS run buffer; 1 cursor atomic per run ----------
__global__ __launch_bounds__(256)
void scatter_kernel(const float* __restrict__ points,
                    const int* __restrict__ choices,
                    const float* __restrict__ A,
                    const float* __restrict__ b,
                    const float* __restrict__ fc,
                    const float* __restrict__ minv,
                    const float* __restrict__ rangev,
                    const int* __restrict__ skipp,
                    const unsigned* __restrict__ scanb,   // = hist after scan
                    const unsigned* __restrict__ sums,
                    unsigned* __restrict__ records)
{
    __shared__ float sA[NF * 4], sB[NF * 2], sFC[NF];
    __shared__ unsigned sCur[NTILES];
    __shared__ unsigned rb[RBCAP][256];     // run buffer: bank = t%32, conflict-free
    const int t = threadIdx.x;
    const int blk = blockIdx.x;
    if (t < NF * 4) sA[t] = A[t];
    if (t < NF * 2) sB[t] = b[t];
    if (t < NF)     sFC[t] = fc[t];
    for (int tt = t; tt < NTILES; tt += 256)
        sCur[tt] = scanb[tt * NBLK + blk] + sums[tt];
    __syncthreads();

    const int base = blk * PPB;
    const float mx = minv[0], my = minv[1], rx = rangev[0], ry = rangev[1];
    const int skip = skipp[0];

    unsigned ctile = INV, clen = 0;

    for (int p = 0; p < PPT; ++p) {
        const int n = base + p * 256 + t;
        float x = points[3*n], y = points[3*n+1], c = points[3*n+2];
        for (int k = 0; k < KSTEPS; ++k) {
            const int idx = choices[k * NPTS + n];
            const float nx = sA[idx*4+0]*x + sA[idx*4+1]*y + sB[idx*2+0];
            const float ny = sA[idx*4+2]*x + sA[idx*4+3]*y + sB[idx*2+1];
            c = 0.5f * (c + sFC[idx]);
            x = nx; y = ny;
            const int xb = (int)((nx - mx) * rx);
            const int yb = (int)((ny - my) * ry);
            if (k >= skip && (unsigned)xb < (unsigned)W && (unsigned)yb < (unsigned)H) {
                const unsigned tile = (unsigned)(((xb >> 6) << 5) | (yb >> 5));
                if (tile != ctile || clen == RBCAP) {
                    if (clen) {   // flush run: one atomic, contiguous stores
                        unsigned pos = atomicAdd(&sCur[ctile], clen);
                        for (unsigned j = 0; j < clen; ++j)
                            records[pos + j] = rb[j][t];
                    }
                    ctile = tile; clen = 0;
                }
                const unsigned q = (unsigned)__float2int_rn(c * (100.0f * QSCALE));
                rb[clen][t] = (q << 11) | (unsigned)(((xb & 63) << 5) | (yb & 31));
                ++clen;
            }
        }
        // run stays open across points: adjacent same-tile records still merge
    }
    if (clen) {
        unsigned pos = atomicAdd(&sCur[ctile], clen);
        for (unsigned j = 0; j < clen; ++j)
            records[pos + j] = rb[j][t];
    }
}

// ---------- K4: dense-tile LDS accumulate, u64 packed fixed-point atomics ----------
__global__ __launch_bounds__(K4_BS)
void accum_slot_kernel(const unsigned* __restrict__ records,
                       const unsigned* __restrict__ sums,
                       const unsigned* __restrict__ dstart,
                       const unsigned* __restrict__ vstart,
                       const float* __restrict__ palette,
                       float* __restrict__ slots)
{
    __shared__ unsigned long long img01[TPIX];   // ch0|ch1 packed, 16 KB
    __shared__ unsigned long long img23[TPIX];   // ch2|ch3 packed, 16 KB
    __shared__ float4 sPal[FID + 1];
    __shared__ unsigned tstart[NTILES + 1];
    __shared__ unsigned dst[NTILES + 1];
    __shared__ unsigned vst[NTILES];
    const int t = threadIdx.x;
    for (int i = t; i < NTILES + 1; i += K4_BS) { tstart[i] = sums[i]; dst[i] = dstart[i]; }
    for (int i = t; i < NTILES; i += K4_BS) vst[i] = vstart[i];
    for (int i = t; i < (FID + 1) * 4; i += K4_BS) ((float*)sPal)[i] = palette[i];
    __syncthreads();

    const unsigned dtotal = dst[NTILES];
    const unsigned r0 = (unsigned)blockIdx.x * CHUNK;
    if (r0 >= dtotal) return;
    const unsigned r1 = min(r0 + (unsigned)CHUNK, dtotal);

    int lo = 0, hi = NTILES;
    while (lo < hi) {
        const int mid = (lo + hi + 1) >> 1;
        if (dst[mid] <= r0) lo = mid; else hi = mid - 1;
    }

    for (int tile = lo; tile < NTILES && dst[tile] < r1; ++tile) {
        const unsigned sd = max(dst[tile], r0);
        const unsigned ed = min(dst[tile + 1], r1);
        if (sd >= ed) continue;
        const unsigned gs = tstart[tile] + (sd - dst[tile]);
        const unsigned ge = gs + (ed - sd);

        for (int i = t; i < TPIX; i += K4_BS) { img01[i] = 0ull; img23[i] = 0ull; }
        __syncthreads();

        // 2 u64 atomics per record. Fixed-point 2^17: 8192 x 2^17 = 2^30 < 2^31.
        for (unsigned i = gs + t; i < ge; i += K4_BS) {
            int pix; float v0, v1, v2, v3;
            decode_rec(records[i], sPal, pix, v0, v1, v2, v3);
            atomicAdd(&img01[pix], pack2(v0, v1));
            atomicAdd(&img23[pix], pack2(v2, v3));
        }
        __syncthreads();

        const unsigned slot = vst[tile] + ((unsigned)blockIdx.x - dst[tile] / CHUNK);
        float* sp = slots + (size_t)slot * (4 * TPIX);
        for (int i2 = t; i2 < TPIX; i2 += K4_BS) {
            const unsigned long long a = img01[i2];
            const unsigned long long bb = img23[i2];
            sp[0 * TPIX + i2] = (float)(unsigned)(a  & 0xFFFFFFFFu) * FXSI;
            sp[1 * TPIX + i2] = (float)(unsigned)(a  >> 32)         * FXSI;
            sp[2 * TPIX + i2] = (float)(unsigned)(bb & 0xFFFFFFFFu) * FXSI;
            sp[3 * TPIX + i2] = (float)(unsigned)(bb >> 32)         * FXSI;
        }
        __syncthreads();
    }
}

// ---------- K5: per-tile reduce of slots + sparse records (+raw0) -> out ----------
__global__ __launch_bounds__(256)
void reduce_kernel(const float* __restrict__ slots,
                   const unsigned* __restrict__ vstart,
                   const unsigned* __restrict__ sums,
                   const unsigned* __restrict__ records,
                   const float* __restrict__ palette,
                   const float* __restrict__ raw0,
                   float* __restrict__ out)
{
    __shared__ unsigned long long l01[256];      // sparse acc, ch0|ch1
    __shared__ unsigned long long l23[256];      // sparse acc, ch2|ch3
    __shared__ float4 sPal[FID + 1];
    const int T = blockIdx.x >> 3;          // tile
    const int g = blockIdx.x & 7;           // 256-px group
    const int t = threadIdx.x;
    for (int i = t; i < (FID + 1) * 4; i += 256) ((float*)sPal)[i] = palette[i];
    l01[t] = 0ull; l23[t] = 0ull;
    __syncthreads();

    const unsigned v0 = vstart[T], v1 = vstart[T + 1];
    const unsigned s = sums[T], e = sums[T + 1];
    const int ch = t >> 6;
    const int f4 = ch * (TPIX / 4) + (g * 256 >> 2) + (t & 63);

    float4 acc = {0.f, 0.f, 0.f, 0.f};
    for (unsigned v = v0; v < v1; ++v) {
        const float4 sv = ((const float4*)(slots + (size_t)v * (4 * TPIX)))[f4];
        acc.x += sv.x; acc.y += sv.y; acc.z += sv.z; acc.w += sv.w;
    }

    if (v0 == v1 && e > s) {
        // sparse tile (<=4096 records): 2^17 fixed-point safe (4096*2^17 = 2^29)
        for (unsigned i = s + t; i < e; i += 256) {
            const unsigned r = records[i];
            const int pix = (int)(r & 2047u);
            if ((pix >> 8) == g) {
                int dummy; float w0, w1, w2, w3;
                decode_rec(r, sPal, dummy, w0, w1, w2, w3);
                const int lp = pix & 255;
                atomicAdd(&l01[lp], pack2(w0, w1));
                atomicAdd(&l23[lp], pack2(w2, w3));
            }
        }
    }
    __syncthreads();

    const int lbase = (t & 63) * 4;
#pragma unroll
    for (int j = 0; j < 4; ++j) {
        const int lp = lbase + j;
        float v;
        if (ch == 0)      v = (float)(unsigned)(l01[lp] & 0xFFFFFFFFu) * FXSI;
        else if (ch == 1) v = (float)(unsigned)(l01[lp] >> 32) * FXSI;
        else if (ch == 2) v = (float)(unsigned)(l23[lp] & 0xFFFFFFFFu) * FXSI;
        else              v = (float)(unsigned)(l23[lp] >> 32) * FXSI;
        if (j == 0) acc.x += v;
        else if (j == 1) acc.y += v;
        else if (j == 2) acc.z += v;
        else acc.w += v;
    }

    const int lpix = g * 256 + lbase;
    const int px = lpix >> 5, py = lpix & 31;
    const int tx = T >> 5, ty = T & 31;
    const size_t o = (size_t)ch * HW + (size_t)(tx * 64 + px) * W + (ty * 32 + py);
    const float4 r = *(const float4*)(raw0 + o);
    acc.x += r.x; acc.y += r.y; acc.z += r.z; acc.w += r.w;
    *(float4*)(out + o) = acc;
}

// ---------- Fallback: direct planar atomics ----------
__global__ __launch_bounds__(256)
void flame_kernel_planar(const float* __restrict__ points,
                         const int* __restrict__ choices,
                         const float* __restrict__ A,
                         const float* __restrict__ b,
                         const float* __restrict__ fc,
                         const float* __restrict__ palette,
                         const float* __restrict__ min_vec,
                         const float* __restrict__ range_vec,
                         const int* __restrict__ skipp,
                         float* __restrict__ out)
{
    __shared__ float sA[NF * 4];
    __shared__ float sB[NF * 2];
    __shared__ float sFC[NF];
    __shared__ float4 sPal[FID + 1];
    const int t = threadIdx.x;
    if (t < NF * 4) sA[t] = A[t];
    if (t < NF * 2) sB[t] = b[t];
    if (t < NF)     sFC[t] = fc[t];
    for (int i = t; i < (FID + 1) * 4; i += 256) ((float*)sPal)[i] = palette[i];
    __syncthreads();

    const int n = blockIdx.x * 256 + t;
    float x = points[3 * n], y = points[3 * n + 1], c = points[3 * n + 2];
    const float mx = min_vec[0], my = min_vec[1];
    const float rx = range_vec[0], ry = range_vec[1];
    const int skip = skipp[0];

    for (int k = 0; k < KSTEPS; ++k) {
        const int idx = choices[k * NPTS + n];
        const float nx = sA[idx*4+0]*x + sA[idx*4+1]*y + sB[idx*2+0];
        const float ny = sA[idx*4+2]*x + sA[idx*4+3]*y + sB[idx*2+1];
        c = 0.5f * (c + sFC[idx]);
        x = nx; y = ny;
        const float _c = c * (float)FID;
        const float cf = floorf(_c);
        const float tt = _c - cf;
        const int cfi = (int)fminf(fmaxf(cf, 0.f), (float)FID);
        const int cci = (int)fminf(fmaxf(ceilf(_c), 0.f), (float)FID);
        const float4 pc = sPal[cci];
        const float4 pf = sPal[cfi];
        const int xb = (int)((nx - mx) * rx);
        const int yb = (int)((ny - my) * ry);
        if (k >= skip && (unsigned)xb < (unsigned)W && (unsigned)yb < (unsigned)H) {
            const int p = xb * W + yb;
            const float omt = 1.f - tt;
            atomicAdd(out + p + 0 * HW, tt * pc.x + omt * pf.x);
            atomicAdd(out + p + 1 * HW, tt * pc.y + omt * pf.y);
            atomicAdd(out + p + 2 * HW, tt * pc.z + omt * pf.z);
            atomicAdd(out + p + 3 * HW, tt * pc.w + omt * pf.w);
        }
    }
}

extern "C" void kernel_launch(void* const* d_in, const int* in_sizes, int n_in,
                              void* d_out, int out_size, void* d_ws, size_t ws_size,
                              hipStream_t stream) {
    const float* points    = (const float*)d_in[0];
    const int*   choices   = (const int*)d_in[1];
    const float* A         = (const float*)d_in[2];
    const float* b         = (const float*)d_in[3];
    const float* fc        = (const float*)d_in[4];
    const float* palette   = (const float*)d_in[5];
    const float* min_vec   = (const float*)d_in[6];
    const float* range_vec = (const float*)d_in[7];
    const float* raw0      = (const float*)d_in[8];
    const int*   skipp     = (const int*)d_in[9];
    float* out = (float*)d_out;
    const size_t img_bytes = (size_t)4 * HW * sizeof(float);   // 16 MB

    const size_t hist_off = 0;                                  // 2 MiB
    const size_t rec_off  = (size_t)SEG_N * 4;
    const size_t rec_cap  = (size_t)MAXREC * 4;                 // 84 MB (u32 records)
    const size_t sums_off = rec_off + rec_cap;
    const size_t dst_off  = sums_off + 4096;
    const size_t vst_off  = dst_off + 4096;
    const size_t slot_off = vst_off + 4096;
    const size_t slot_cap = (size_t)MAXVIS * (4 * TPIX) * sizeof(float);  // 100.7 MB
    const size_t need1    = slot_off + slot_cap;               // ~187 MB

    unsigned* hist = (unsigned*)((char*)d_ws + hist_off);
    unsigned* sums = (unsigned*)((char*)d_ws + sums_off);
    unsigned* recs = (unsigned*)((char*)d_ws + rec_off);

    if (ws_size >= need1) {
        unsigned* dstart = (unsigned*)((char*)d_ws + dst_off);
        unsigned* vstart = (unsigned*)((char*)d_ws + vst_off);
        float*    slots  = (float*)((char*)d_ws + slot_off);

        count_kernel<<<NBLK, 256, 0, stream>>>(
            points, choices, A, b, min_vec, range_vec, skipp, hist);
        scan1_kernel<<<SEG_N / 1024, 1024, 0, stream>>>(hist, sums);
        scan2v_kernel<<<1, 512, 0, stream>>>(sums, dstart, vstart);
        scatter_kernel<<<NBLK, 256, 0, stream>>>(
            points, choices, A, b, fc, min_vec, range_vec, skipp, hist, sums, recs);
        accum_slot_kernel<<<K4_GRID, K4_BS, 0, stream>>>(
            recs, sums, dstart, vstart, palette, slots);
        reduce_kernel<<<NTILES * 8, 256, 0, stream>>>(
            slots, vstart, sums, recs, palette, raw0, out);
    } else {
        hipMemcpyAsync(out, raw0, img_bytes, hipMemcpyDeviceToDevice, stream);
        flame_kernel_planar<<<NPTS / 256, 256, 0, stream>>>(
            points, choices, A, b, fc, palette, min_vec, range_vec, skipp, out);
    }
}